// Round 20
// baseline (136.406 us; speedup 1.0000x reference)
//
#include <hip/hip_runtime.h>
#include <hip/hip_bf16.h>
#include <hip/hip_fp16.h>
#include <cstdint>
#include <cstddef>

#define N_B 4
#define D_F 512
#define L_S 2048
#define H_N 8
#define DH  64
#define C3  (3*D_F)   // 1536

typedef __attribute__((ext_vector_type(8)))  short short8;
typedef __attribute__((ext_vector_type(4)))  float f32x4;
typedef __attribute__((ext_vector_type(16))) float f32x16;

#if __has_builtin(__builtin_amdgcn_exp2f)
#define EXP2F(x) __builtin_amdgcn_exp2f(x)
#else
#define EXP2F(x) __expf((x) * 0.6931471805599453f)
#endif

__device__ __forceinline__ unsigned int pk_bf16(float a, float b) {
    __hip_bfloat162 h = __float22bfloat162_rn(float2{a, b});
    union { __hip_bfloat162 h; unsigned int u; } cv;
    cv.h = h;
    return cv.u;
}
__device__ __forceinline__ unsigned short bf16_rn(float f) {
    union { float f; unsigned int u; } c; c.f = f;
    unsigned int r = c.u + 0x7FFF + ((c.u >> 16) & 1);
    return (unsigned short)(r >> 16);
}
__device__ __forceinline__ float bf16_f(unsigned short h) {
    union { unsigned int u; float f; } c; c.u = ((unsigned int)h) << 16;
    return c.f;
}
__device__ __forceinline__ unsigned short f16_bits(float f) {
    union { __half h; unsigned short u; } c;
    c.h = __float2half(f);
    return c.u;
}

// async global->LDS, 16B per lane; lds base must be wave-uniform; global addr per-lane.
__device__ __forceinline__ void gll16(const unsigned short* g, unsigned short* l) {
    __builtin_amdgcn_global_load_lds(
        (const __attribute__((address_space(1))) unsigned int*)g,
        (__attribute__((address_space(3))) unsigned int*)l,
        16, 0, 0);
}

// ---------------------------------------------------------------------------
// Weight convert: w_qkv -> bf16, w_proj -> fp16 (single term each).
// ---------------------------------------------------------------------------
__global__ __launch_bounds__(256) void cvt_w(const float* __restrict__ wq,
                                             unsigned short* __restrict__ wq_h,
                                             int n4q,
                                             const float* __restrict__ wp,
                                             unsigned short* __restrict__ wp_h,
                                             int n4p) {
    int i = blockIdx.x * 256 + threadIdx.x;
    if (i < n4q) {
        float4 v = ((const float4*)wq)[i];
        ushort4 h;
        h.x = bf16_rn(v.x); h.y = bf16_rn(v.y); h.z = bf16_rn(v.z); h.w = bf16_rn(v.w);
        ((ushort4*)wq_h)[i] = h;
    } else if (i < n4q + n4p) {
        int idx = i - n4q;
        float4 v = ((const float4*)wp)[idx];
        ushort4 h;
        h.x = f16_bits(v.x); h.y = f16_bits(v.y); h.z = f16_bits(v.z); h.w = f16_bits(v.w);
        ((ushort4*)wp_h)[idx] = h;
    }
}

// ---------------------------------------------------------------------------
// Transpose+convert: x[n][c][l] f32 -> xT[n][l][c] bf16 (unchanged).
// ---------------------------------------------------------------------------
__global__ __launch_bounds__(256) void cvt_xT(const float* __restrict__ x,
                                              unsigned short* __restrict__ xT,
                                              int C) {
    __shared__ float tile[64][65];
    const int tid = threadIdx.x;
    const int l0  = blockIdx.x * 64;
    const int c0  = blockIdx.y * 64;
    const int n   = blockIdx.z;

    const float* xn = x + (size_t)n * C * L_S;
#pragma unroll
    for (int r = 0; r < 16; ++r) {
        int c = r * 4 + (tid >> 6);
        int l = tid & 63;
        tile[c][l] = xn[(size_t)(c0 + c) * L_S + l0 + l];
    }
    __syncthreads();

    unsigned short* xn_t = xT + (size_t)n * L_S * C;
#pragma unroll
    for (int r = 0; r < 8; ++r) {
        int l  = r * 8 + (tid >> 5);
        int cp = tid & 31;
        unsigned int pk = pk_bf16(tile[cp * 2][l], tile[cp * 2 + 1][l]);
        *(unsigned int*)&xn_t[(size_t)(l0 + l) * C + c0 + cp * 2] = pk;
    }
}

// ---------------------------------------------------------------------------
// MFMA GEMM v4: BK=64 (32 MFMAs per barrier pair, half the drains of v3).
// Y[n][o][l] = sum_c W[o][c] * XT[n][l][c]. Tile 128x128, 4 waves.
// LDS: Wt/Xt[8 planes][128 rows][8 c] = 16KB each. grid: (L/128, O/128, N).
// ---------------------------------------------------------------------------
template<int FP16, int OUT_BF16>
__global__ __launch_bounds__(256) void gemm_mfma4(const unsigned short* __restrict__ Wd,
                                                  const unsigned short* __restrict__ XT,
                                                  void* __restrict__ Y,
                                                  int O, int C) {
    __shared__ unsigned short Wt[8][128 * 8];
    __shared__ unsigned short Xt[8][128 * 8];

    const int tid  = threadIdx.x;
    const int lane = tid & 63;
    const int w    = tid >> 6;
    const int g    = lane >> 4;
    const int c    = lane & 15;
    const int wr   = (w >> 1) * 64;
    const int wc   = (w & 1) * 64;
    const int l0   = blockIdx.x * 128;
    const int o0   = blockIdx.y * 128;
    const int n    = blockIdx.z;

    const unsigned short* XTn = XT + (size_t)n * L_S * C;

    const int rhalf = (w & 1) * 64;
    const int pb    = w >> 1;           // plane base: stages planes pb, pb+2, pb+4, pb+6
    const size_t wrow = (size_t)(o0 + rhalf + lane) * C;
    const size_t xrow = (size_t)(l0 + rhalf + lane) * C;

    f32x4 acc[4][4];
#pragma unroll
    for (int mt = 0; mt < 4; ++mt)
#pragma unroll
        for (int nt = 0; nt < 4; ++nt) acc[mt][nt] = (f32x4){0.f, 0.f, 0.f, 0.f};

    for (int c0 = 0; c0 < C; c0 += 64) {
        __syncthreads();
#pragma unroll
        for (int pp = 0; pp < 4; ++pp) {
            int p = pb + pp * 2;
            gll16(Wd  + wrow + c0 + p * 8, &Wt[p][rhalf * 8]);
            gll16(XTn + xrow + c0 + p * 8, &Xt[p][rhalf * 8]);
        }
        __syncthreads();

#pragma unroll
        for (int half = 0; half < 2; ++half) {
            short8 a0[4], b0[4];
#pragma unroll
            for (int mt = 0; mt < 4; ++mt) a0[mt] = *(short8*)&Wt[half * 4 + g][(wr + mt * 16 + c) * 8];
#pragma unroll
            for (int nt = 0; nt < 4; ++nt) b0[nt] = *(short8*)&Xt[half * 4 + g][(wc + nt * 16 + c) * 8];

#pragma unroll
            for (int mt = 0; mt < 4; ++mt)
#pragma unroll
                for (int nt = 0; nt < 4; ++nt) {
                    if (FP16)
                        acc[mt][nt] = __builtin_amdgcn_mfma_f32_16x16x32_f16(a0[mt], b0[nt], acc[mt][nt], 0, 0, 0);
                    else
                        acc[mt][nt] = __builtin_amdgcn_mfma_f32_16x16x32_bf16(a0[mt], b0[nt], acc[mt][nt], 0, 0, 0);
                }
        }
    }

#pragma unroll
    for (int mt = 0; mt < 4; ++mt) {
#pragma unroll
        for (int r = 0; r < 4; ++r) {
            int oo = o0 + wr + mt * 16 + g * 4 + r;
            size_t rowbase = ((size_t)n * O + oo) * L_S;
#pragma unroll
            for (int nt = 0; nt < 4; ++nt) {
                int ll = l0 + wc + nt * 16 + c;
                if (OUT_BF16)
                    ((unsigned short*)Y)[rowbase + ll] = bf16_rn(acc[mt][nt][r]);
                else
                    ((float*)Y)[rowbase + ll] = acc[mt][nt][r];
            }
        }
    }
}

// ---------------------------------------------------------------------------
// Fused dwconv + l2norm + pack for Q/K heads. Q pre-scaled by temp*log2(e).
// ---------------------------------------------------------------------------
__global__ __launch_bounds__(256) void fused_qk2(const unsigned short* __restrict__ qkv_bf,
                                                 const float* __restrict__ w_dw,
                                                 const float* __restrict__ temp,
                                                 unsigned short* __restrict__ Qb,
                                                 unsigned short* __restrict__ Kb) {
    __shared__ unsigned short rows[64 * 264];
    __shared__ float wsm[192];
    const int tid = threadIdx.x;
    const int l0  = blockIdx.x * 256;
    const int gg  = blockIdx.y;
    const int n   = blockIdx.z;
    const int head = gg & 7;
    const int ch0  = (gg < 8) ? head * 64 : 512 + head * 64;

    if (tid < 192) wsm[tid] = w_dw[ch0 * 3 + tid];

    const unsigned short* base = qkv_bf + ((size_t)n * C3 + ch0) * L_S;
    for (int f = tid; f < 2048; f += 256) {
        int e = f >> 5, s = f & 31;
        *(uint4*)&rows[e * 264 + s * 8] = *(const uint4*)&base[(size_t)e * L_S + l0 + s * 8];
    }
    if (tid < 64) {
        rows[tid * 264 + 256] = (l0 > 0) ? base[(size_t)tid * L_S + l0 - 1] : (unsigned short)0;
    } else if (tid < 128) {
        int e = tid - 64;
        rows[e * 264 + 257] = (l0 + 256 < L_S) ? base[(size_t)e * L_S + l0 + 256] : (unsigned short)0;
    }
    __syncthreads();

    const int lL = tid;
    const int iL = (lL == 0)   ? 256 : lL - 1;
    const int iR = (lL == 255) ? 257 : lL + 1;
    float y[64];
    float s = 0.f;
#pragma unroll
    for (int e = 0; e < 64; ++e) {
        float a = bf16_f(rows[e * 264 + iL]);
        float b = bf16_f(rows[e * 264 + lL]);
        float d = bf16_f(rows[e * 264 + iR]);
        float v = wsm[e * 3 + 0] * a + wsm[e * 3 + 1] * b + wsm[e * 3 + 2] * d;
        y[e] = v;
        s += v * v;
    }
    float sc = 1.0f / fmaxf(sqrtf(s), 1e-12f);
    if (gg < 8) sc *= temp[head] * 1.44269504088896f;   // fold t*log2(e) into Q

    const int l = l0 + tid;
    unsigned short* dst = ((gg < 8) ? Qb : Kb) + (size_t)(n * H_N + head) * 8 * L_S * 8;
#pragma unroll
    for (int p = 0; p < 8; ++p) {
        uint4 pk = make_uint4(pk_bf16(y[8 * p + 0] * sc, y[8 * p + 1] * sc),
                              pk_bf16(y[8 * p + 2] * sc, y[8 * p + 3] * sc),
                              pk_bf16(y[8 * p + 4] * sc, y[8 * p + 5] * sc),
                              pk_bf16(y[8 * p + 6] * sc, y[8 * p + 7] * sc));
        *(uint4*)&dst[((size_t)p * L_S + l) * 8] = pk;
    }
}

// ---------------------------------------------------------------------------
// Fused dwconv + pack for V heads (unchanged).
// ---------------------------------------------------------------------------
__global__ __launch_bounds__(256) void fused_v2(const unsigned short* __restrict__ qkv_bf,
                                                const float* __restrict__ w_dw,
                                                unsigned short* __restrict__ Vb) {
    const int tid = threadIdx.x;
    const int e   = tid & 63;
    const int jp  = blockIdx.x * 4 + (tid >> 6);
    const int h   = blockIdx.y;
    const int n   = blockIdx.z;
    const int ch  = 1024 + h * 64 + e;
    const unsigned short* row = qkv_bf + ((size_t)n * C3 + ch) * L_S;
    const int k0 = jp * 8;

    uint4 mv = *(const uint4*)&row[k0];
    unsigned int lw = (jp > 0)   ? *(const unsigned int*)&row[k0 - 2] : 0u;
    unsigned int rw = (jp < 255) ? *(const unsigned int*)&row[k0 + 8] : 0u;

    float v[10];
    v[0] = bf16_f((unsigned short)(lw >> 16));
    v[1] = bf16_f((unsigned short)(mv.x & 0xFFFF));
    v[2] = bf16_f((unsigned short)(mv.x >> 16));
    v[3] = bf16_f((unsigned short)(mv.y & 0xFFFF));
    v[4] = bf16_f((unsigned short)(mv.y >> 16));
    v[5] = bf16_f((unsigned short)(mv.z & 0xFFFF));
    v[6] = bf16_f((unsigned short)(mv.z >> 16));
    v[7] = bf16_f((unsigned short)(mv.w & 0xFFFF));
    v[8] = bf16_f((unsigned short)(mv.w >> 16));
    v[9] = bf16_f((unsigned short)(rw & 0xFFFF));

    float w0 = w_dw[ch * 3 + 0], w1 = w_dw[ch * 3 + 1], w2 = w_dw[ch * 3 + 2];
    unsigned int o[4];
#pragma unroll
    for (int i = 0; i < 4; ++i) {
        float y0 = w0 * v[2 * i + 0] + w1 * v[2 * i + 1] + w2 * v[2 * i + 2];
        float y1 = w0 * v[2 * i + 1] + w1 * v[2 * i + 2] + w2 * v[2 * i + 3];
        o[i] = pk_bf16(y0, y1);
    }
    uint4 ov = make_uint4(o[0], o[1], o[2], o[3]);
    *(uint4*)&Vb[(((size_t)(n * H_N + h) * 256 + jp) * 512) + e * 8] = ov;
}

// ---------------------------------------------------------------------------
// Flash attention v15b (unchanged from R19 champion).
// ---------------------------------------------------------------------------
__global__ __launch_bounds__(512, 4) void attn15b(const unsigned short* __restrict__ Qb,
                                                  const unsigned short* __restrict__ Kb,
                                                  const unsigned short* __restrict__ Vb,
                                                  unsigned short* __restrict__ aoT) {
    __shared__ unsigned short KV[16384];   // 32KB: group g2 at g2*8192 {K 4096 u16, V 4096 u16}
    __shared__ float smA[128], smB[128];
    float* OtB = (float*)KV;               // 32KB overlay post-loop

    const int tid  = threadIdx.x;
    const int lane = tid & 63;
    const int w    = tid >> 6;     // 0..7
    const int g2   = w >> 2;       // key-split group
    const int wv   = w & 3;        // wave within group
    const int c32  = lane & 31;
    const int h    = lane >> 5;
    const int q0   = blockIdx.x * 128;
    const int hd   = blockIdx.y;
    const int n    = blockIdx.z;

    const size_t hb = (size_t)(n * H_N + hd);
    const unsigned short* Qh = Qb + hb * 8 * L_S * 8;
    const unsigned short* Kh = Kb + hb * 8 * L_S * 8;
    const unsigned short* Vh = Vb + hb * 256 * 512;

    bool dirA;
    {
        auto tp = __builtin_amdgcn_permlane32_swap((int)lane, (int)(lane + 64), false, false);
        unsigned xv = (unsigned)tp[0];
        bool ok = (lane < 32) ? true : (xv == (unsigned)(lane + 32));
        dirA = (__ballot(ok) == 0xFFFFFFFFFFFFFFFFull);
    }

    short8 qa[4];
#pragma unroll
    for (int es = 0; es < 4; ++es)
        qa[es] = *(const short8*)&Qh[((size_t)(es * 2 + h) * L_S + q0 + wv * 32 + c32) * 8];

    unsigned short* myKV = KV + g2 * 8192;

    f32x16 acc0, acc1;
#pragma unroll
    for (int i = 0; i < 16; ++i) { acc0[i] = 0.f; acc1[i] = 0.f; }
    float sumP = 0.f;

    for (int it = 0; it < 16; ++it) {
        const int kb = (it * 2 + g2) * 64;

        __syncthreads();
        gll16(Kh + ((size_t)wv * L_S + kb + lane) * 8,            myKV + wv * 512);
        gll16(Kh + ((size_t)(wv + 4) * L_S + kb + lane) * 8,      myKV + (wv + 4) * 512);
        gll16(Vh + ((size_t)(kb / 8 + wv) * 512 + lane * 8),      myKV + 4096 + wv * 512);
        gll16(Vh + ((size_t)(kb / 8 + wv + 4) * 512 + lane * 8),  myKV + 4096 + (wv + 4) * 512);
        __syncthreads();

        const unsigned short* B = myKV;

        f32x16 sf0, sf1;
#pragma unroll
        for (int i = 0; i < 16; ++i) { sf0[i] = 0.f; sf1[i] = 0.f; }
#pragma unroll
        for (int es = 0; es < 4; ++es) {
            short8 ka0 = *(short8*)&B[(es * 2 + h) * 512 + c32 * 8];
            short8 ka1 = *(short8*)&B[(es * 2 + h) * 512 + (32 + c32) * 8];
            sf0 = __builtin_amdgcn_mfma_f32_32x32x16_bf16(ka0, qa[es], sf0, 0, 0, 0);
            sf1 = __builtin_amdgcn_mfma_f32_32x32x16_bf16(ka1, qa[es], sf1, 0, 0, 0);
        }

        short8 pa[4];
        {
            unsigned int W_[16];
#pragma unroll
            for (int G = 0; G < 4; ++G) {
                float p0 = EXP2F(sf0[4*G+0]);
                float p1 = EXP2F(sf0[4*G+1]);
                float p2 = EXP2F(sf0[4*G+2]);
                float p3 = EXP2F(sf0[4*G+3]);
                sumP += (p0 + p1) + (p2 + p3);
                W_[2*G]   = pk_bf16(p0, p1);
                W_[2*G+1] = pk_bf16(p2, p3);
                float u0 = EXP2F(sf1[4*G+0]);
                float u1 = EXP2F(sf1[4*G+1]);
                float u2 = EXP2F(sf1[4*G+2]);
                float u3 = EXP2F(sf1[4*G+3]);
                sumP += (u0 + u1) + (u2 + u3);
                W_[8+2*G]   = pk_bf16(u0, u1);
                W_[8+2*G+1] = pk_bf16(u2, u3);
            }
#pragma unroll
            for (int ks = 0; ks < 4; ++ks) {
                unsigned w0 = dirA ? W_[4*ks]   : W_[4*ks+2];
                unsigned w2 = dirA ? W_[4*ks+2] : W_[4*ks];
                unsigned w1 = dirA ? W_[4*ks+1] : W_[4*ks+3];
                unsigned w3 = dirA ? W_[4*ks+3] : W_[4*ks+1];
                auto r02 = __builtin_amdgcn_permlane32_swap((int)w0, (int)w2, false, false);
                auto r13 = __builtin_amdgcn_permlane32_swap((int)w1, (int)w3, false, false);
                unsigned a0 = dirA ? (unsigned)r02[0] : (unsigned)r02[1];
                unsigned a2 = dirA ? (unsigned)r02[1] : (unsigned)r02[0];
                unsigned a1 = dirA ? (unsigned)r13[0] : (unsigned)r13[1];
                unsigned a3 = dirA ? (unsigned)r13[1] : (unsigned)r13[0];
                uint4 pu = make_uint4(a0, a1, a2, a3);
                pa[ks] = *(short8*)&pu;
            }
        }

#pragma unroll
        for (int ks = 0; ks < 4; ++ks) {
            short8 vb0 = *(short8*)&B[4096 + (ks * 2 + h) * 512 + c32 * 8];
            short8 vb1 = *(short8*)&B[4096 + (ks * 2 + h) * 512 + (32 + c32) * 8];
            acc0 = __builtin_amdgcn_mfma_f32_32x32x16_bf16(pa[ks], vb0, acc0, 0, 0, 0);
            acc1 = __builtin_amdgcn_mfma_f32_32x32x16_bf16(pa[ks], vb1, acc1, 0, 0, 0);
        }
    }
    __syncthreads();

    sumP += __shfl_xor(sumP, 32);

    if (g2 == 1) {
        smB[wv * 32 + c32] = sumP;
#pragma unroll
        for (int r = 0; r < 16; ++r) {
            int ql = (r & 3) + 8 * (r >> 2) + 4 * h;
            int qg = wv * 32 + ql;
            OtB[qg * 64 + c32]      = acc0[r];
            OtB[qg * 64 + 32 + c32] = acc1[r];
        }
    } else {
        smA[wv * 32 + c32] = sumP;
    }
    __syncthreads();

    if (g2 == 0) {
        float b0[16], b1[16], inv[16];
#pragma unroll
        for (int r = 0; r < 16; ++r) {
            int ql = (r & 3) + 8 * (r >> 2) + 4 * h;
            int qg = wv * 32 + ql;
            b0[r] = OtB[qg * 64 + c32];
            b1[r] = OtB[qg * 64 + 32 + c32];
            inv[r] = 1.0f / (smA[qg] + smB[qg]);
        }
#pragma unroll
        for (int r = 0; r < 16; ++r) {
            int ql = (r & 3) + 8 * (r >> 2) + 4 * h;
            int qg = wv * 32 + ql;
            OtB[qg * 64 + (c32 ^ (qg & 31))]        = (acc0[r] + b0[r]) * inv[r];
            OtB[qg * 64 + ((32 + c32) ^ (qg & 31))] = (acc1[r] + b1[r]) * inv[r];
        }
    }
    __syncthreads();

    for (int tt = tid; tt < 8192; tt += 512) {
        int qq = tt >> 6, e = tt & 63;
        float v = OtB[qq * 64 + (e ^ (qq & 31))];
        size_t off = ((size_t)n * L_S + q0 + qq) * D_F + hd * 64 + e;
        aoT[off] = f16_bits(v);
    }
}

// ---------------------------------------------------------------------------
extern "C" void kernel_launch(void* const* d_in, const int* in_sizes, int n_in,
                              void* d_out, int out_size, void* d_ws, size_t ws_size,
                              hipStream_t stream) {
    const float* x      = (const float*)d_in[0];   // (4, 512, 2048)
    const float* w_qkv  = (const float*)d_in[1];   // (1536, 512)
    const float* w_dw   = (const float*)d_in[2];   // (1536, 3)
    const float* w_proj = (const float*)d_in[3];   // (512, 512)
    const float* temp   = (const float*)d_in[4];   // (8)
    float* out = (float*)d_out;

    const size_t WQE = (size_t)C3 * D_F;           // 786,432
    const size_t WPE = (size_t)D_F * D_F;          // 262,144

    char* ws = (char*)d_ws;
    unsigned short* qkv_bf = (unsigned short*)ws;               // 25,165,824 B
    unsigned short* Qb     = (unsigned short*)(ws + 25165824);  //  8,388,608 B
    unsigned short* Kb     = (unsigned short*)(ws + 33554432);  //  8,388,608 B
    unsigned short* Vb     = (unsigned short*)(ws + 41943040);  //  8,388,608 B
    unsigned short* xT     = (unsigned short*)(ws + 50331648);  //  8,388,608 B
    unsigned short* wq_h   = (unsigned short*)(ws + 58720256);  //  1,572,864 B
    unsigned short* wp_h   = (unsigned short*)(ws + 60293120);  //    524,288 B (fp16)
    unsigned short* aoT    = xT;   // reuse: xT consumed by QKV gemm before attn writes (fp16)

    // 0) x transpose/convert + weight converts
    cvt_xT<<<dim3(L_S / 64, D_F / 64, N_B), 256, 0, stream>>>(x, xT, D_F);
    {
        int n4q = (int)(WQE / 4), n4p = (int)(WPE / 4);
        cvt_w<<<dim3((n4q + n4p + 255) / 256), 256, 0, stream>>>(
            w_qkv, wq_h, n4q, w_proj, wp_h, n4p);
    }

    // 1) QKV 1x1 conv: bf16 MFMA, BK=64 gll16-staged -> bf16
    gemm_mfma4<0, 1><<<dim3(L_S / 128, C3 / 128, N_B), 256, 0, stream>>>(
        wq_h, xT, qkv_bf, C3, D_F);

    // 2) fused dwconv (+l2norm, Q pre-scale) + MFMA-layout bf16 pack
    fused_qk2<<<dim3(L_S / 256, 16, N_B), 256, 0, stream>>>(qkv_bf, w_dw, temp, Qb, Kb);
    fused_v2<<<dim3(64, H_N, N_B), 256, 0, stream>>>(qkv_bf, w_dw, Vb);

    // 3) attention (R19 champion, unchanged) -> fp16 aoT
    attn15b<<<dim3(L_S / 128, H_N, N_B), 512, 0, stream>>>(Qb, Kb, Vb, aoT);

    // 4) single-term fp16 proj GEMM (BK=64) -> fp32 out
    gemm_mfma4<1, 0><<<dim3(L_S / 128, D_F / 128, N_B), 256, 0, stream>>>(
        wp_h, aoT, out, D_F, D_F);
}

// Round 21
// 133.642 us; speedup vs baseline: 1.0207x; 1.0207x over previous
//
#include <hip/hip_runtime.h>
#include <hip/hip_bf16.h>
#include <hip/hip_fp16.h>
#include <cstdint>
#include <cstddef>

#define N_B 4
#define D_F 512
#define L_S 2048
#define H_N 8
#define DH  64
#define C3  (3*D_F)   // 1536

typedef __attribute__((ext_vector_type(8)))  short short8;
typedef __attribute__((ext_vector_type(4)))  float f32x4;
typedef __attribute__((ext_vector_type(16))) float f32x16;

#if __has_builtin(__builtin_amdgcn_exp2f)
#define EXP2F(x) __builtin_amdgcn_exp2f(x)
#else
#define EXP2F(x) __expf((x) * 0.6931471805599453f)
#endif

__device__ __forceinline__ unsigned int pk_bf16(float a, float b) {
    __hip_bfloat162 h = __float22bfloat162_rn(float2{a, b});
    union { __hip_bfloat162 h; unsigned int u; } cv;
    cv.h = h;
    return cv.u;
}
__device__ __forceinline__ unsigned short bf16_rn(float f) {
    union { float f; unsigned int u; } c; c.f = f;
    unsigned int r = c.u + 0x7FFF + ((c.u >> 16) & 1);
    return (unsigned short)(r >> 16);
}
__device__ __forceinline__ float bf16_f(unsigned short h) {
    union { unsigned int u; float f; } c; c.u = ((unsigned int)h) << 16;
    return c.f;
}
__device__ __forceinline__ unsigned short f16_bits(float f) {
    union { __half h; unsigned short u; } c;
    c.h = __float2half(f);
    return c.u;
}

// async global->LDS, 16B per lane; lds base must be wave-uniform; global addr per-lane.
__device__ __forceinline__ void gll16(const unsigned short* g, unsigned short* l) {
    __builtin_amdgcn_global_load_lds(
        (const __attribute__((address_space(1))) unsigned int*)g,
        (__attribute__((address_space(3))) unsigned int*)l,
        16, 0, 0);
}

// ---------------------------------------------------------------------------
// Weight convert: w_qkv -> bf16, w_proj -> fp16 (single term each).
// ---------------------------------------------------------------------------
__global__ __launch_bounds__(256) void cvt_w(const float* __restrict__ wq,
                                             unsigned short* __restrict__ wq_h,
                                             int n4q,
                                             const float* __restrict__ wp,
                                             unsigned short* __restrict__ wp_h,
                                             int n4p) {
    int i = blockIdx.x * 256 + threadIdx.x;
    if (i < n4q) {
        float4 v = ((const float4*)wq)[i];
        ushort4 h;
        h.x = bf16_rn(v.x); h.y = bf16_rn(v.y); h.z = bf16_rn(v.z); h.w = bf16_rn(v.w);
        ((ushort4*)wq_h)[i] = h;
    } else if (i < n4q + n4p) {
        int idx = i - n4q;
        float4 v = ((const float4*)wp)[idx];
        ushort4 h;
        h.x = f16_bits(v.x); h.y = f16_bits(v.y); h.z = f16_bits(v.z); h.w = f16_bits(v.w);
        ((ushort4*)wp_h)[idx] = h;
    }
}

// ---------------------------------------------------------------------------
// Transpose+convert: x[n][c][l] f32 -> xT[n][l][c] bf16.
// ---------------------------------------------------------------------------
__global__ __launch_bounds__(256) void cvt_xT(const float* __restrict__ x,
                                              unsigned short* __restrict__ xT,
                                              int C) {
    __shared__ float tile[64][65];
    const int tid = threadIdx.x;
    const int l0  = blockIdx.x * 64;
    const int c0  = blockIdx.y * 64;
    const int n   = blockIdx.z;

    const float* xn = x + (size_t)n * C * L_S;
#pragma unroll
    for (int r = 0; r < 16; ++r) {
        int c = r * 4 + (tid >> 6);
        int l = tid & 63;
        tile[c][l] = xn[(size_t)(c0 + c) * L_S + l0 + l];
    }
    __syncthreads();

    unsigned short* xn_t = xT + (size_t)n * L_S * C;
#pragma unroll
    for (int r = 0; r < 8; ++r) {
        int l  = r * 8 + (tid >> 5);
        int cp = tid & 31;
        unsigned int pk = pk_bf16(tile[cp * 2][l], tile[cp * 2 + 1][l]);
        *(unsigned int*)&xn_t[(size_t)(l0 + l) * C + c0 + cp * 2] = pk;
    }
}

// ---------------------------------------------------------------------------
// MFMA GEMM v3 (R19 champion): single-term, dtype-templated, BK=32.
// Y[n][o][l] = sum_c W[o][c] * XT[n][l][c]. Tile 128x128, 4 waves,
// both tiles staged via global_load_lds. grid: (L/128, O/128, N).
// ---------------------------------------------------------------------------
template<int FP16, int OUT_BF16>
__global__ __launch_bounds__(256) void gemm_mfma3(const unsigned short* __restrict__ Wd,
                                                  const unsigned short* __restrict__ XT,
                                                  void* __restrict__ Y,
                                                  int O, int C) {
    __shared__ unsigned short Wt[4][128 * 8];
    __shared__ unsigned short Xt[4][128 * 8];

    const int tid  = threadIdx.x;
    const int lane = tid & 63;
    const int w    = tid >> 6;
    const int g    = lane >> 4;
    const int c    = lane & 15;
    const int wr   = (w >> 1) * 64;
    const int wc   = (w & 1) * 64;
    const int l0   = blockIdx.x * 128;
    const int o0   = blockIdx.y * 128;
    const int n    = blockIdx.z;

    const unsigned short* XTn = XT + (size_t)n * L_S * C;

    const int rhalf = (w & 1) * 64;
    const int cpA   = w >> 1;
    const int cpB   = 2 + (w >> 1);
    const size_t wrowA = (size_t)(o0 + rhalf + lane) * C;
    const size_t xrowA = (size_t)(l0 + rhalf + lane) * C;

    f32x4 acc[4][4];
#pragma unroll
    for (int mt = 0; mt < 4; ++mt)
#pragma unroll
        for (int nt = 0; nt < 4; ++nt) acc[mt][nt] = (f32x4){0.f, 0.f, 0.f, 0.f};

    for (int c0 = 0; c0 < C; c0 += 32) {
        __syncthreads();
        gll16(Wd  + wrowA + c0 + cpA * 8, &Wt[cpA][rhalf * 8]);
        gll16(Wd  + wrowA + c0 + cpB * 8, &Wt[cpB][rhalf * 8]);
        gll16(XTn + xrowA + c0 + cpA * 8, &Xt[cpA][rhalf * 8]);
        gll16(XTn + xrowA + c0 + cpB * 8, &Xt[cpB][rhalf * 8]);
        __syncthreads();

        short8 a0[4], b0[4];
#pragma unroll
        for (int mt = 0; mt < 4; ++mt) a0[mt] = *(short8*)&Wt[g][(wr + mt * 16 + c) * 8];
#pragma unroll
        for (int nt = 0; nt < 4; ++nt) b0[nt] = *(short8*)&Xt[g][(wc + nt * 16 + c) * 8];

#pragma unroll
        for (int mt = 0; mt < 4; ++mt)
#pragma unroll
            for (int nt = 0; nt < 4; ++nt) {
                if (FP16)
                    acc[mt][nt] = __builtin_amdgcn_mfma_f32_16x16x32_f16(a0[mt], b0[nt], acc[mt][nt], 0, 0, 0);
                else
                    acc[mt][nt] = __builtin_amdgcn_mfma_f32_16x16x32_bf16(a0[mt], b0[nt], acc[mt][nt], 0, 0, 0);
            }
    }

#pragma unroll
    for (int mt = 0; mt < 4; ++mt) {
#pragma unroll
        for (int r = 0; r < 4; ++r) {
            int oo = o0 + wr + mt * 16 + g * 4 + r;
            size_t rowbase = ((size_t)n * O + oo) * L_S;
#pragma unroll
            for (int nt = 0; nt < 4; ++nt) {
                int ll = l0 + wc + nt * 16 + c;
                if (OUT_BF16)
                    ((unsigned short*)Y)[rowbase + ll] = bf16_rn(acc[mt][nt][r]);
                else
                    ((float*)Y)[rowbase + ll] = acc[mt][nt][r];
            }
        }
    }
}

// ---------------------------------------------------------------------------
// Fused dwconv + l2norm + pack for Q/K heads. Q pre-scaled by temp*log2(e).
// ---------------------------------------------------------------------------
__global__ __launch_bounds__(256) void fused_qk2(const unsigned short* __restrict__ qkv_bf,
                                                 const float* __restrict__ w_dw,
                                                 const float* __restrict__ temp,
                                                 unsigned short* __restrict__ Qb,
                                                 unsigned short* __restrict__ Kb) {
    __shared__ unsigned short rows[64 * 264];
    __shared__ float wsm[192];
    const int tid = threadIdx.x;
    const int l0  = blockIdx.x * 256;
    const int gg  = blockIdx.y;
    const int n   = blockIdx.z;
    const int head = gg & 7;
    const int ch0  = (gg < 8) ? head * 64 : 512 + head * 64;

    if (tid < 192) wsm[tid] = w_dw[ch0 * 3 + tid];

    const unsigned short* base = qkv_bf + ((size_t)n * C3 + ch0) * L_S;
    for (int f = tid; f < 2048; f += 256) {
        int e = f >> 5, s = f & 31;
        *(uint4*)&rows[e * 264 + s * 8] = *(const uint4*)&base[(size_t)e * L_S + l0 + s * 8];
    }
    if (tid < 64) {
        rows[tid * 264 + 256] = (l0 > 0) ? base[(size_t)tid * L_S + l0 - 1] : (unsigned short)0;
    } else if (tid < 128) {
        int e = tid - 64;
        rows[e * 264 + 257] = (l0 + 256 < L_S) ? base[(size_t)e * L_S + l0 + 256] : (unsigned short)0;
    }
    __syncthreads();

    const int lL = tid;
    const int iL = (lL == 0)   ? 256 : lL - 1;
    const int iR = (lL == 255) ? 257 : lL + 1;
    float y[64];
    float s = 0.f;
#pragma unroll
    for (int e = 0; e < 64; ++e) {
        float a = bf16_f(rows[e * 264 + iL]);
        float b = bf16_f(rows[e * 264 + lL]);
        float d = bf16_f(rows[e * 264 + iR]);
        float v = wsm[e * 3 + 0] * a + wsm[e * 3 + 1] * b + wsm[e * 3 + 2] * d;
        y[e] = v;
        s += v * v;
    }
    float sc = 1.0f / fmaxf(sqrtf(s), 1e-12f);
    if (gg < 8) sc *= temp[head] * 1.44269504088896f;   // fold t*log2(e) into Q

    const int l = l0 + tid;
    unsigned short* dst = ((gg < 8) ? Qb : Kb) + (size_t)(n * H_N + head) * 8 * L_S * 8;
#pragma unroll
    for (int p = 0; p < 8; ++p) {
        uint4 pk = make_uint4(pk_bf16(y[8 * p + 0] * sc, y[8 * p + 1] * sc),
                              pk_bf16(y[8 * p + 2] * sc, y[8 * p + 3] * sc),
                              pk_bf16(y[8 * p + 4] * sc, y[8 * p + 5] * sc),
                              pk_bf16(y[8 * p + 6] * sc, y[8 * p + 7] * sc));
        *(uint4*)&dst[((size_t)p * L_S + l) * 8] = pk;
    }
}

// ---------------------------------------------------------------------------
// Fused dwconv + pack for V heads.
// ---------------------------------------------------------------------------
__global__ __launch_bounds__(256) void fused_v2(const unsigned short* __restrict__ qkv_bf,
                                                const float* __restrict__ w_dw,
                                                unsigned short* __restrict__ Vb) {
    const int tid = threadIdx.x;
    const int e   = tid & 63;
    const int jp  = blockIdx.x * 4 + (tid >> 6);
    const int h   = blockIdx.y;
    const int n   = blockIdx.z;
    const int ch  = 1024 + h * 64 + e;
    const unsigned short* row = qkv_bf + ((size_t)n * C3 + ch) * L_S;
    const int k0 = jp * 8;

    uint4 mv = *(const uint4*)&row[k0];
    unsigned int lw = (jp > 0)   ? *(const unsigned int*)&row[k0 - 2] : 0u;
    unsigned int rw = (jp < 255) ? *(const unsigned int*)&row[k0 + 8] : 0u;

    float v[10];
    v[0] = bf16_f((unsigned short)(lw >> 16));
    v[1] = bf16_f((unsigned short)(mv.x & 0xFFFF));
    v[2] = bf16_f((unsigned short)(mv.x >> 16));
    v[3] = bf16_f((unsigned short)(mv.y & 0xFFFF));
    v[4] = bf16_f((unsigned short)(mv.y >> 16));
    v[5] = bf16_f((unsigned short)(mv.z & 0xFFFF));
    v[6] = bf16_f((unsigned short)(mv.z >> 16));
    v[7] = bf16_f((unsigned short)(mv.w & 0xFFFF));
    v[8] = bf16_f((unsigned short)(mv.w >> 16));
    v[9] = bf16_f((unsigned short)(rw & 0xFFFF));

    float w0 = w_dw[ch * 3 + 0], w1 = w_dw[ch * 3 + 1], w2 = w_dw[ch * 3 + 2];
    unsigned int o[4];
#pragma unroll
    for (int i = 0; i < 4; ++i) {
        float y0 = w0 * v[2 * i + 0] + w1 * v[2 * i + 1] + w2 * v[2 * i + 2];
        float y1 = w0 * v[2 * i + 1] + w1 * v[2 * i + 2] + w2 * v[2 * i + 3];
        o[i] = pk_bf16(y0, y1);
    }
    uint4 ov = make_uint4(o[0], o[1], o[2], o[3]);
    *(uint4*)&Vb[(((size_t)(n * H_N + h) * 256 + jp) * 512) + e * 8] = ov;
}

// ---------------------------------------------------------------------------
// Flash attention v15b (R19 champion): key-split 8-wave, single-buffer 33KB
// LDS, direct-register Q, p=2^sf softmax (constant cancels in ratio),
// permlane32_swap P exchange, fp16 aoT output. grid: (L/128, H, N).
// ---------------------------------------------------------------------------
__global__ __launch_bounds__(512, 4) void attn15b(const unsigned short* __restrict__ Qb,
                                                  const unsigned short* __restrict__ Kb,
                                                  const unsigned short* __restrict__ Vb,
                                                  unsigned short* __restrict__ aoT) {
    __shared__ unsigned short KV[16384];   // 32KB: group g2 at g2*8192 {K 4096 u16, V 4096 u16}
    __shared__ float smA[128], smB[128];
    float* OtB = (float*)KV;               // 32KB overlay post-loop

    const int tid  = threadIdx.x;
    const int lane = tid & 63;
    const int w    = tid >> 6;     // 0..7
    const int g2   = w >> 2;       // key-split group
    const int wv   = w & 3;        // wave within group
    const int c32  = lane & 31;
    const int h    = lane >> 5;
    const int q0   = blockIdx.x * 128;
    const int hd   = blockIdx.y;
    const int n    = blockIdx.z;

    const size_t hb = (size_t)(n * H_N + hd);
    const unsigned short* Qh = Qb + hb * 8 * L_S * 8;
    const unsigned short* Kh = Kb + hb * 8 * L_S * 8;
    const unsigned short* Vh = Vb + hb * 256 * 512;

    bool dirA;
    {
        auto tp = __builtin_amdgcn_permlane32_swap((int)lane, (int)(lane + 64), false, false);
        unsigned xv = (unsigned)tp[0];
        bool ok = (lane < 32) ? true : (xv == (unsigned)(lane + 32));
        dirA = (__ballot(ok) == 0xFFFFFFFFFFFFFFFFull);
    }

    short8 qa[4];
#pragma unroll
    for (int es = 0; es < 4; ++es)
        qa[es] = *(const short8*)&Qh[((size_t)(es * 2 + h) * L_S + q0 + wv * 32 + c32) * 8];

    unsigned short* myKV = KV + g2 * 8192;

    f32x16 acc0, acc1;
#pragma unroll
    for (int i = 0; i < 16; ++i) { acc0[i] = 0.f; acc1[i] = 0.f; }
    float sumP = 0.f;

    for (int it = 0; it < 16; ++it) {
        const int kb = (it * 2 + g2) * 64;

        __syncthreads();
        gll16(Kh + ((size_t)wv * L_S + kb + lane) * 8,            myKV + wv * 512);
        gll16(Kh + ((size_t)(wv + 4) * L_S + kb + lane) * 8,      myKV + (wv + 4) * 512);
        gll16(Vh + ((size_t)(kb / 8 + wv) * 512 + lane * 8),      myKV + 4096 + wv * 512);
        gll16(Vh + ((size_t)(kb / 8 + wv + 4) * 512 + lane * 8),  myKV + 4096 + (wv + 4) * 512);
        __syncthreads();

        const unsigned short* B = myKV;

        f32x16 sf0, sf1;
#pragma unroll
        for (int i = 0; i < 16; ++i) { sf0[i] = 0.f; sf1[i] = 0.f; }
#pragma unroll
        for (int es = 0; es < 4; ++es) {
            short8 ka0 = *(short8*)&B[(es * 2 + h) * 512 + c32 * 8];
            short8 ka1 = *(short8*)&B[(es * 2 + h) * 512 + (32 + c32) * 8];
            sf0 = __builtin_amdgcn_mfma_f32_32x32x16_bf16(ka0, qa[es], sf0, 0, 0, 0);
            sf1 = __builtin_amdgcn_mfma_f32_32x32x16_bf16(ka1, qa[es], sf1, 0, 0, 0);
        }

        short8 pa[4];
        {
            unsigned int W_[16];
#pragma unroll
            for (int G = 0; G < 4; ++G) {
                float p0 = EXP2F(sf0[4*G+0]);
                float p1 = EXP2F(sf0[4*G+1]);
                float p2 = EXP2F(sf0[4*G+2]);
                float p3 = EXP2F(sf0[4*G+3]);
                sumP += (p0 + p1) + (p2 + p3);
                W_[2*G]   = pk_bf16(p0, p1);
                W_[2*G+1] = pk_bf16(p2, p3);
                float u0 = EXP2F(sf1[4*G+0]);
                float u1 = EXP2F(sf1[4*G+1]);
                float u2 = EXP2F(sf1[4*G+2]);
                float u3 = EXP2F(sf1[4*G+3]);
                sumP += (u0 + u1) + (u2 + u3);
                W_[8+2*G]   = pk_bf16(u0, u1);
                W_[8+2*G+1] = pk_bf16(u2, u3);
            }
#pragma unroll
            for (int ks = 0; ks < 4; ++ks) {
                unsigned w0 = dirA ? W_[4*ks]   : W_[4*ks+2];
                unsigned w2 = dirA ? W_[4*ks+2] : W_[4*ks];
                unsigned w1 = dirA ? W_[4*ks+1] : W_[4*ks+3];
                unsigned w3 = dirA ? W_[4*ks+3] : W_[4*ks+1];
                auto r02 = __builtin_amdgcn_permlane32_swap((int)w0, (int)w2, false, false);
                auto r13 = __builtin_amdgcn_permlane32_swap((int)w1, (int)w3, false, false);
                unsigned a0 = dirA ? (unsigned)r02[0] : (unsigned)r02[1];
                unsigned a2 = dirA ? (unsigned)r02[1] : (unsigned)r02[0];
                unsigned a1 = dirA ? (unsigned)r13[0] : (unsigned)r13[1];
                unsigned a3 = dirA ? (unsigned)r13[1] : (unsigned)r13[0];
                uint4 pu = make_uint4(a0, a1, a2, a3);
                pa[ks] = *(short8*)&pu;
            }
        }

#pragma unroll
        for (int ks = 0; ks < 4; ++ks) {
            short8 vb0 = *(short8*)&B[4096 + (ks * 2 + h) * 512 + c32 * 8];
            short8 vb1 = *(short8*)&B[4096 + (ks * 2 + h) * 512 + (32 + c32) * 8];
            acc0 = __builtin_amdgcn_mfma_f32_32x32x16_bf16(pa[ks], vb0, acc0, 0, 0, 0);
            acc1 = __builtin_amdgcn_mfma_f32_32x32x16_bf16(pa[ks], vb1, acc1, 0, 0, 0);
        }
    }
    __syncthreads();

    sumP += __shfl_xor(sumP, 32);

    if (g2 == 1) {
        smB[wv * 32 + c32] = sumP;
#pragma unroll
        for (int r = 0; r < 16; ++r) {
            int ql = (r & 3) + 8 * (r >> 2) + 4 * h;
            int qg = wv * 32 + ql;
            OtB[qg * 64 + c32]      = acc0[r];
            OtB[qg * 64 + 32 + c32] = acc1[r];
        }
    } else {
        smA[wv * 32 + c32] = sumP;
    }
    __syncthreads();

    if (g2 == 0) {
        float b0[16], b1[16], inv[16];
#pragma unroll
        for (int r = 0; r < 16; ++r) {
            int ql = (r & 3) + 8 * (r >> 2) + 4 * h;
            int qg = wv * 32 + ql;
            b0[r] = OtB[qg * 64 + c32];
            b1[r] = OtB[qg * 64 + 32 + c32];
            inv[r] = 1.0f / (smA[qg] + smB[qg]);
        }
#pragma unroll
        for (int r = 0; r < 16; ++r) {
            int ql = (r & 3) + 8 * (r >> 2) + 4 * h;
            int qg = wv * 32 + ql;
            OtB[qg * 64 + (c32 ^ (qg & 31))]        = (acc0[r] + b0[r]) * inv[r];
            OtB[qg * 64 + ((32 + c32) ^ (qg & 31))] = (acc1[r] + b1[r]) * inv[r];
        }
    }
    __syncthreads();

    for (int tt = tid; tt < 8192; tt += 512) {
        int qq = tt >> 6, e = tt & 63;
        float v = OtB[qq * 64 + (e ^ (qq & 31))];
        size_t off = ((size_t)n * L_S + q0 + qq) * D_F + hd * 64 + e;
        aoT[off] = f16_bits(v);
    }
}

// ---------------------------------------------------------------------------
extern "C" void kernel_launch(void* const* d_in, const int* in_sizes, int n_in,
                              void* d_out, int out_size, void* d_ws, size_t ws_size,
                              hipStream_t stream) {
    const float* x      = (const float*)d_in[0];   // (4, 512, 2048)
    const float* w_qkv  = (const float*)d_in[1];   // (1536, 512)
    const float* w_dw   = (const float*)d_in[2];   // (1536, 3)
    const float* w_proj = (const float*)d_in[3];   // (512, 512)
    const float* temp   = (const float*)d_in[4];   // (8)
    float* out = (float*)d_out;

    const size_t WQE = (size_t)C3 * D_F;           // 786,432
    const size_t WPE = (size_t)D_F * D_F;          // 262,144

    char* ws = (char*)d_ws;
    unsigned short* qkv_bf = (unsigned short*)ws;               // 25,165,824 B
    unsigned short* Qb     = (unsigned short*)(ws + 25165824);  //  8,388,608 B
    unsigned short* Kb     = (unsigned short*)(ws + 33554432);  //  8,388,608 B
    unsigned short* Vb     = (unsigned short*)(ws + 41943040);  //  8,388,608 B
    unsigned short* xT     = (unsigned short*)(ws + 50331648);  //  8,388,608 B
    unsigned short* wq_h   = (unsigned short*)(ws + 58720256);  //  1,572,864 B
    unsigned short* wp_h   = (unsigned short*)(ws + 60293120);  //    524,288 B (fp16)
    unsigned short* aoT    = xT;   // reuse: xT consumed by QKV gemm before attn writes (fp16)

    // 0) x transpose/convert + weight converts
    cvt_xT<<<dim3(L_S / 64, D_F / 64, N_B), 256, 0, stream>>>(x, xT, D_F);
    {
        int n4q = (int)(WQE / 4), n4p = (int)(WPE / 4);
        cvt_w<<<dim3((n4q + n4p + 255) / 256), 256, 0, stream>>>(
            w_qkv, wq_h, n4q, w_proj, wp_h, n4p);
    }

    // 1) QKV 1x1 conv: bf16 MFMA, BK=32 gll16-staged -> bf16
    gemm_mfma3<0, 1><<<dim3(L_S / 128, C3 / 128, N_B), 256, 0, stream>>>(
        wq_h, xT, qkv_bf, C3, D_F);

    // 2) fused dwconv (+l2norm, Q pre-scale) + MFMA-layout bf16 pack
    fused_qk2<<<dim3(L_S / 256, 16, N_B), 256, 0, stream>>>(qkv_bf, w_dw, temp, Qb, Kb);
    fused_v2<<<dim3(64, H_N, N_B), 256, 0, stream>>>(qkv_bf, w_dw, Vb);

    // 3) attention (R19 champion) -> fp16 aoT
    attn15b<<<dim3(L_S / 128, H_N, N_B), 512, 0, stream>>>(Qb, Kb, Vb, aoT);

    // 4) single-term fp16 proj GEMM (BK=32) -> fp32 out
    gemm_mfma3<1, 0><<<dim3(L_S / 128, D_F / 128, N_B), 256, 0, stream>>>(
        wp_h, aoT, out, D_F, D_F);
}